// Round 8
// baseline (734.542 us; speedup 1.0000x reference)
//
#include <hip/hip_runtime.h>
#include <hip/hip_bf16.h>
#include <math.h>

typedef __bf16 bf16x8 __attribute__((ext_vector_type(8)));
typedef float  f32x4  __attribute__((ext_vector_type(4)));

__device__ __forceinline__ float sigm(float x)  { return 1.f/(1.f+__expf(-x)); }
__device__ __forceinline__ float tanh_f(float x){ return 2.f/(1.f+__expf(-2.f*x)) - 1.f; }
__device__ __forceinline__ float b2f(unsigned short u){
  unsigned int x = ((unsigned int)u) << 16; return __uint_as_float(x);
}
__device__ __forceinline__ unsigned short f2b(float v){
  __hip_bfloat16 h = __float2bfloat16(v); return *(unsigned short*)&h;
}
__device__ __forceinline__ void glds16(const void* g, void* l) {
  __builtin_amdgcn_global_load_lds(
      (const __attribute__((address_space(1))) unsigned int*)g,
      (__attribute__((address_space(3))) unsigned int*)l, 16, 0, 0);
}
__device__ __forceinline__ bf16x8 bzero() {
  bf16x8 v;
  #pragma unroll
  for (int i = 0; i < 8; ++i) v[i] = (__bf16)0.0f;
  return v;
}
// barrier with LDS-only ordering: skip the vmcnt(0) drain __syncthreads would emit.
__device__ __forceinline__ void barrier_lds() {
  asm volatile("s_waitcnt lgkmcnt(0)\n\ts_barrier" ::: "memory");
}

// ---------------- upsample(2x, align_corners) + channel concat -> NHWC bf16 --------------
__global__ __launch_bounds__(256) void k_upcat(const float* __restrict__ x1,
                                               const float* __restrict__ x2,
                                               __hip_bfloat16* __restrict__ X0) {
  int idx = blockIdx.x*256 + threadIdx.x;
  int c = idx & 255;
  int w = (idx >> 8) & 63;
  int h = (idx >> 14) & 63;
  int n = idx >> 20;
  float v;
  if (c < 128) {
    v = x2[((n*128 + c)*64 + h)*64 + w];
  } else {
    int cc = c - 128;
    float py = (h*31.0f)/63.0f;
    int ly = (int)py; int hy = min(ly+1, 31); float fy = py - (float)ly;
    float px = (w*31.0f)/63.0f;
    int lx = (int)px; int hx = min(lx+1, 31); float fx = px - (float)lx;
    const float* p = x1 + (size_t)(n*128 + cc)*1024;
    float v00 = p[ly*32+lx], v01 = p[ly*32+hx];
    float v10 = p[hy*32+lx], v11 = p[hy*32+hx];
    v = (1.f-fy)*((1.f-fx)*v00 + fx*v01) + fy*((1.f-fx)*v10 + fx*v11);
  }
  X0[idx] = __float2bfloat16(v);
}

// ---------------- Wih concat -> bf16 [1024][256]; biasc[1024] = bih+bhh ------------------
__global__ __launch_bounds__(256) void k_wih_prep(
    const float* __restrict__ Wf, const float* __restrict__ Wb,
    const float* __restrict__ bif, const float* __restrict__ bhf,
    const float* __restrict__ bib, const float* __restrict__ bhb,
    __hip_bfloat16* __restrict__ wihc, float* __restrict__ biasc) {
  int idx = blockIdx.x*256 + threadIdx.x;     // 1024*256
  int n = idx >> 8, k = idx & 255;
  float v = (n < 512) ? Wf[n*256 + k] : Wb[(n-512)*256 + k];
  wihc[idx] = __float2bfloat16(v);
  if (idx < 1024) biasc[idx] = (idx < 512) ? bif[idx] + bhf[idx]
                                           : bib[idx-512] + bhb[idx-512];
}

// ---------------- xg GEMM -> xg[dir][t][g][u][s] bf16 (seq-innermost planar) -------------
__global__ __launch_bounds__(256) void k_xg_gemm(
    const __hip_bfloat16* __restrict__ Xin,
    const __hip_bfloat16* __restrict__ Wihc,
    const float* __restrict__ biasc,
    __hip_bfloat16* __restrict__ xg) {
  __shared__ __align__(16) unsigned short sa[128][72];
  __shared__ __align__(16) unsigned short sw[128][72];
  int bx = blockIdx.x;                 // 256: t = bx>>2, seq0 = (bx&3)*128
  int t = bx >> 2, seq0 = (bx & 3) << 7;
  int n0 = blockIdx.y << 7;
  int tid = threadIdx.x, lane = tid & 63, wid = tid >> 6;
  int wm = wid >> 1, wn = wid & 1;
  int l15 = lane & 15, quad = lane >> 4;
  f32x4 acc[4][4];
  #pragma unroll
  for (int i = 0; i < 4; ++i)
    #pragma unroll
    for (int j = 0; j < 4; ++j) acc[i][j] = (f32x4){0.f,0.f,0.f,0.f};

  for (int k0 = 0; k0 < 256; k0 += 64) {
    __syncthreads();
    for (int idx = tid; idx < 2048; idx += 256) {
      int row = idx >> 4, c4 = (idx & 15) << 2;
      *(ushort4*)&sa[row][c4] = *(const ushort4*)((const unsigned short*)Xin +
          (size_t)((seq0 + row)*64 + t)*256 + k0 + c4);
      *(ushort4*)&sw[row][c4] = *(const ushort4*)((const unsigned short*)Wihc +
          (size_t)(n0 + row)*256 + k0 + c4);
    }
    __syncthreads();
    #pragma unroll
    for (int k32 = 0; k32 < 64; k32 += 32) {
      bf16x8 af[4], bfr[4];
      #pragma unroll
      for (int mt = 0; mt < 4; ++mt)
        af[mt] = *(const bf16x8*)&sa[wm*64 + mt*16 + l15][k32 + quad*8];
      #pragma unroll
      for (int nt = 0; nt < 4; ++nt)
        bfr[nt] = *(const bf16x8*)&sw[wn*64 + nt*16 + l15][k32 + quad*8];
      #pragma unroll
      for (int mt = 0; mt < 4; ++mt)
        #pragma unroll
        for (int nt = 0; nt < 4; ++nt)
          acc[mt][nt] = __builtin_amdgcn_mfma_f32_16x16x32_bf16(
              af[mt], bfr[nt], acc[mt][nt], 0, 0, 0);
    }
  }
  // epilogue: + bias, bf16, ushort4 stores into [dir][t][g][u][s]
  #pragma unroll
  for (int nt = 0; nt < 4; ++nt) {
    int cg = n0 + wn*64 + nt*16 + l15;        // gate col incl dir
    int dir = cg >> 9;
    int g   = (cg >> 7) & 3;
    int u   = cg & 127;
    float bias = biasc[cg];
    unsigned short* op = (unsigned short*)xg +
        ((size_t)((dir*64 + t)*4 + g)*128 + u)*512;
    #pragma unroll
    for (int mt = 0; mt < 4; ++mt) {
      int sbase = seq0 + wm*64 + mt*16 + quad*4;
      f32x4 a = acc[mt][nt];
      ushort4 o;
      o.x = f2b(a[0] + bias); o.y = f2b(a[1] + bias);
      o.z = f2b(a[2] + bias); o.w = f2b(a[3] + bias);
      *(ushort4*)(op + sbase) = o;
    }
  }
}

// ---------------- recurrent LSTM core v5: 16 seqs/block, 8 waves, cell-aligned gates -----
// grid (32, 2), 512 threads. Wave w's 4 N-tiles = the 4 gate planes of units 16w..16w+15,
// so each lane holds I,F,G,O for its 4 (unit, seq) cells IN-REGISTER: no redistribution.
// xg (layout [dir][t][g][u][s]) loads seed the MFMA C operand (no zero-init, no bias add).
// h double-buffered in LDS; ONE lgkm-only barrier per step.
__global__ __launch_bounds__(512, 1) void k_lstm_rec(
    const __hip_bfloat16* __restrict__ xg,
    const float* __restrict__ WhhF, const float* __restrict__ WhhB,
    __hip_bfloat16* __restrict__ out) {
  const int dir = blockIdx.y;
  const int sb  = blockIdx.x;               // seqs sb*16 .. +16
  const float* Whh = dir ? WhhB : WhhF;
  __shared__ __align__(16) unsigned short hs[2][16][132];  // [buf][seq][unit], stride 132
  const int tid = threadIdx.x, lane = tid & 63, w = tid >> 6;   // wave 0..7
  const int l15 = lane & 15, quad = lane >> 4;
  const int u = w*16 + l15;                 // unit this lane owns (all 4 gate planes)

  // Whh fragments: wf[g][kc] = B[k=kc*32+quad*8..+8][gate g*128+u]
  bf16x8 wf[4][4];
  #pragma unroll
  for (int g = 0; g < 4; ++g)
    #pragma unroll
    for (int kc = 0; kc < 4; ++kc) {
      const float* wp = Whh + (size_t)(g*128 + u)*128 + kc*32 + quad*8;
      float4 w0 = *(const float4*)wp;
      float4 w1 = *(const float4*)(wp + 4);
      bf16x8 f;
      f[0]=(__bf16)w0.x; f[1]=(__bf16)w0.y; f[2]=(__bf16)w0.z; f[3]=(__bf16)w0.w;
      f[4]=(__bf16)w1.x; f[5]=(__bf16)w1.y; f[6]=(__bf16)w1.z; f[7]=(__bf16)w1.w;
      wf[g][kc] = f;
    }
  for (int i = tid; i < 2*16*132; i += 512) ((unsigned short*)hs)[i] = 0;

  float cst[4] = {0.f, 0.f, 0.f, 0.f};      // c for (u, seqs quad*4+0..3)

  const unsigned short* xp = (const unsigned short*)xg +
      (size_t)dir*64*4*128*512 + sb*16 + quad*4;
  ushort4 xv[4], xn[4];
  #define LDX(stp, dst)                                                      \
    {                                                                        \
      int ts_ = (stp) < 64 ? (stp) : 63;                                     \
      int t_  = dir ? 63 - ts_ : ts_;                                        \
      _Pragma("unroll")                                                      \
      for (int g_ = 0; g_ < 4; ++g_)                                         \
        dst[g_] = *(const ushort4*)(xp + ((size_t)(t_*4 + g_)*128 + u)*512); \
    }
  LDX(0, xv);
  __syncthreads();                          // hs init visible

  for (int step = 0; step < 64; ++step) {
    int t = dir ? 63 - step : step;
    int p = step & 1;                       // read buffer
    // A-frags from h(t-1): A[m=l15 seq][k=kc*32+quad*8+j unit]
    bf16x8 af[4];
    #pragma unroll
    for (int kc = 0; kc < 4; ++kc)
      af[kc] = *(const bf16x8*)&hs[p][l15][kc*32 + quad*8];
    // C init = xg pre-activations (bias already folded in by the GEMM)
    f32x4 acc[4];
    #pragma unroll
    for (int g = 0; g < 4; ++g) {
      acc[g][0] = b2f(xv[g].x); acc[g][1] = b2f(xv[g].y);
      acc[g][2] = b2f(xv[g].z); acc[g][3] = b2f(xv[g].w);
    }
    LDX(step + 1, xn);                      // prefetch next step
    #pragma unroll
    for (int kc = 0; kc < 4; ++kc)
      #pragma unroll
      for (int g = 0; g < 4; ++g)
        acc[g] = __builtin_amdgcn_mfma_f32_16x16x32_bf16(
            af[kc], wf[g][kc], acc[g], 0, 0, 0);
    // nonlinearity fully in-register: 4 cells (unit u, seqs quad*4+r)
    #pragma unroll
    for (int r = 0; r < 4; ++r) {
      float I = acc[0][r], F = acc[1][r], G = acc[2][r], O = acc[3][r];
      float cv = sigm(F)*cst[r] + sigm(I)*tanh_f(G);
      float hv = sigm(O)*tanh_f(cv);
      cst[r] = cv;
      unsigned short hb = f2b(hv);
      hs[1 - p][quad*4 + r][u] = hb;
      int gs = sb*16 + quad*4 + r;
      ((unsigned short*)out)[(size_t)(((gs >> 6)*64 + t)*64 + (gs & 63))*256
                             + dir*128 + u] = hb;
    }
    barrier_lds();                          // h(t) visible; WAR on hs[p] resolved
    #pragma unroll
    for (int g = 0; g < 4; ++g) xv[g] = xn[g];
  }
  #undef LDX
}

// ---------------- weight reformat OIHW fp32 -> (ky,kx,co,ci) bf16, optional fold ---------
__global__ __launch_bounds__(256) void k_wrefmt_bf16(const float* __restrict__ src,
                                                     __hip_bfloat16* __restrict__ dst,
                                                     int Ci, int Co, int fold) {
  int idx = blockIdx.x*256 + threadIdx.x;
  int total = 9*Ci*Co;
  if (idx >= total) return;
  int ci = idx % Ci;
  int co = (idx / Ci) % Co;
  int k  = idx / (Ci*Co);             // ky*3+kx
  int CiS = fold ? Ci*2 : Ci;
  float v = src[(size_t)(co*CiS + ci)*9 + k];
  if (fold) v += src[(size_t)(co*CiS + ci + Ci)*9 + k];
  dst[idx] = __float2bfloat16(v);
}

// ---------------- conv3x3 SAME + BN + ReLU, bf16 MFMA, async glds pipeline ---------------
__global__ __launch_bounds__(256, 2) void k_conv3_v2(
    const __hip_bfloat16* __restrict__ inA, const __hip_bfloat16* __restrict__ inB,
    const __hip_bfloat16* __restrict__ wgt,
    const float* __restrict__ gam, const float* __restrict__ bet,
    float* __restrict__ outF, __hip_bfloat16* __restrict__ outB,
    int Cin, int Co, int nchw) {
  __shared__ __align__(16) unsigned short si[2][64][64];   // 16 KB
  __shared__ __align__(16) unsigned short sw[3][128][64];  // 48 KB
  int bx = blockIdx.x;
  int n  = bx >> 5;
  int h0 = (bx & 31) << 1;
  int co0 = blockIdx.y << 7;
  int tid = threadIdx.x;
  int lane = tid & 63;
  int wid  = tid >> 6;
  int wm = wid >> 1;
  int wn = wid & 1;
  int l15 = lane & 15, quad = lane >> 4;

  f32x4 acc[4][4];
  #pragma unroll
  for (int i = 0; i < 4; ++i)
    #pragma unroll
    for (int j = 0; j < 4; ++j) acc[i][j] = (f32x4){0.f,0.f,0.f,0.f};

  int cs = inB ? 256 : Cin;
  for (int ky = 0; ky < 3; ++ky) {
    for (int ci0 = 0; ci0 < Cin; ci0 += 64) {
      const unsigned short* src = (const unsigned short*)inA; int cb = ci0;
      if (inB && ci0 >= 256) { src = (const unsigned short*)inB; cb = ci0 - 256; }
      __syncthreads();
      {
        int r = wid >> 1;
        int ih = h0 + r + ky - 1;
        int half = (wid & 1) << 5;
        if (ih >= 0 && ih <= 63) {
          const unsigned short* gsrc = src + (size_t)((n*64 + ih)*64)*cs + cb;
          int pl = lane >> 3, pc = lane & 7;
          #pragma unroll
          for (int q = 0; q < 4; ++q) {
            int iw = half + q*8 + pl;
            int lc = pc ^ (iw & 7);
            glds16(gsrc + (size_t)iw*cs + lc*8, &si[r][half + q*8][0]);
          }
        } else {
          uint4 z = {0,0,0,0};
          #pragma unroll
          for (int q = 0; q < 4; ++q)
            *(uint4*)(&si[r][half + q*8][0] + lane*8) = z;
        }
      }
      {
        int col = lane >> 3, pc = lane & 7;
        const unsigned short* wk = (const unsigned short*)wgt +
            (size_t)(ky*3*Co + co0)*Cin + ci0;
        #pragma unroll
        for (int j = 0; j < 12; ++j) {
          int s = wid + j*4;
          int kx = s >> 4, co8 = (s & 15) << 3;
          int co = co8 + col;
          int lc = pc ^ (co & 7);
          glds16(wk + (size_t)(kx*Co + co)*Cin + lc*8, &sw[kx][co8][0]);
        }
      }
      __syncthreads();
      #pragma unroll
      for (int kx = 0; kx < 3; ++kx) {
        #pragma unroll
        for (int k32 = 0; k32 < 2; ++k32) {
          bf16x8 af[4], bfr[4];
          #pragma unroll
          for (int mt = 0; mt < 4; ++mt) {
            int iw = mt*16 + l15 + kx - 1;
            int iwc = iw & 63;
            int pc = (k32*4 + quad) ^ (iwc & 7);
            af[mt] = *(const bf16x8*)&si[wm][iwc][pc*8];
            if ((kx == 0 && mt == 0 && l15 == 0) ||
                (kx == 2 && mt == 3 && l15 == 15))
              af[mt] = bzero();
          }
          #pragma unroll
          for (int nt = 0; nt < 4; ++nt) {
            int co = wn*64 + nt*16 + l15;
            int pc = (k32*4 + quad) ^ (co & 7);
            bfr[nt] = *(const bf16x8*)&sw[kx][co][pc*8];
          }
          #pragma unroll
          for (int mt = 0; mt < 4; ++mt)
            #pragma unroll
            for (int nt = 0; nt < 4; ++nt)
              acc[mt][nt] = __builtin_amdgcn_mfma_f32_16x16x32_bf16(
                  af[mt], bfr[nt], acc[mt][nt], 0, 0, 0);
        }
      }
    }
  }
  const float kS = 0.9999950000374997f;   // 1/sqrt(1+1e-5)
  int h = h0 + wm;
  #pragma unroll
  for (int nt = 0; nt < 4; ++nt) {
    int co = co0 + wn*64 + nt*16 + l15;
    float scale = gam[co]*kS, bb = bet[co];
    #pragma unroll
    for (int mt = 0; mt < 4; ++mt) {
      f32x4 a = acc[mt][nt];
      #pragma unroll
      for (int r = 0; r < 4; ++r) {
        int w = mt*16 + quad*4 + r;
        float v = fmaf(a[r], scale, bb);
        v = v > 0.f ? v : 0.f;
        if (nchw) outF[(size_t)((n*Co + co)*64 + h)*64 + w] = v;
        else      outB[(size_t)((n*64 + h)*64 + w)*Co + co] = __float2bfloat16(v);
      }
    }
  }
}

extern "C" void kernel_launch(void* const* d_in, const int* in_sizes, int n_in,
                              void* d_out, int out_size, void* d_ws, size_t ws_size,
                              hipStream_t stream) {
  const float* x1    = (const float*)d_in[0];
  const float* x2    = (const float*)d_in[1];
  const float* Wih_f = (const float*)d_in[2];
  const float* Whh_f = (const float*)d_in[3];
  const float* bih_f = (const float*)d_in[4];
  const float* bhh_f = (const float*)d_in[5];
  const float* Wih_b = (const float*)d_in[6];
  const float* Whh_b = (const float*)d_in[7];
  const float* bih_b = (const float*)d_in[8];
  const float* bhh_b = (const float*)d_in[9];
  const float* c2_w1 = (const float*)d_in[10];
  const float* c2_g1 = (const float*)d_in[11];
  const float* c2_b1 = (const float*)d_in[12];
  const float* c2_w2 = (const float*)d_in[13];
  const float* c2_g2 = (const float*)d_in[14];
  const float* c2_b2 = (const float*)d_in[15];
  const float* cv_w1 = (const float*)d_in[16];
  const float* cv_g1 = (const float*)d_in[17];
  const float* cv_b1 = (const float*)d_in[18];
  const float* cv_w2 = (const float*)d_in[19];
  const float* cv_g2 = (const float*)d_in[20];
  const float* cv_b2 = (const float*)d_in[21];

  // ---- workspace layout (~107 MB, aliased) ----
  char* base = (char*)d_ws;
  const size_t SLOTB = 16777216ull;                 // bf16 activation slot
  __hip_bfloat16* Xb  = (__hip_bfloat16*)(base);
  __hip_bfloat16* Sb  = (__hip_bfloat16*)(base);
  __hip_bfloat16* XG  = (__hip_bfloat16*)(base + SLOTB);
  __hip_bfloat16* D2  = (__hip_bfloat16*)(base + SLOTB);
  __hip_bfloat16* D2b = (__hip_bfloat16*)(base + 2*SLOTB);
  __hip_bfloat16* RT  = (__hip_bfloat16*)(base + SLOTB + 67108864ull);
  __hip_bfloat16* D1  = RT;
  char* wq = base + SLOTB + 67108864ull + SLOTB;
  __hip_bfloat16* wihc  = (__hip_bfloat16*)wq;
  float*          biasc = (float*)(wq + 524288);
  char* cw = wq + 528384;
  __hip_bfloat16* w1f    = (__hip_bfloat16*)(cw);
  __hip_bfloat16* w1full = (__hip_bfloat16*)(cw + 1179648);
  __hip_bfloat16* w2r    = (__hip_bfloat16*)(cw + 3538944);
  __hip_bfloat16* wv1    = (__hip_bfloat16*)(cw + 4718592);
  __hip_bfloat16* wv2    = (__hip_bfloat16*)(cw + 5308416);

  // weight prep
  k_wih_prep<<<1024, 256, 0, stream>>>(Wih_f, Wih_b, bih_f, bhh_f, bih_b, bhh_b,
                                       wihc, biasc);
  k_wrefmt_bf16<<<(9*256*256+255)/256, 256, 0, stream>>>(c2_w1, w1f,    256, 256, 1);
  k_wrefmt_bf16<<<(9*512*256+255)/256, 256, 0, stream>>>(c2_w1, w1full, 512, 256, 0);
  k_wrefmt_bf16<<<(9*256*256+255)/256, 256, 0, stream>>>(c2_w2, w2r,    256, 256, 0);
  k_wrefmt_bf16<<<(9*256*128+255)/256, 256, 0, stream>>>(cv_w1, wv1,    256, 128, 0);
  k_wrefmt_bf16<<<(9*128*128+255)/256, 256, 0, stream>>>(cv_w2, wv2,    128, 128, 0);

  // upsample + concat -> Xb (NHWC bf16)
  k_upcat<<<32768, 256, 0, stream>>>(x1, x2, Xb);

  // pass 1 (rows): xg = Xb @ Wih^T + b ; recurrent -> RT (transposed layout)
  k_xg_gemm<<<dim3(256, 8), 256, 0, stream>>>(Xb, wihc, biasc, XG);
  k_lstm_rec<<<dim3(32, 2), 512, 0, stream>>>(XG, Whh_f, Whh_b, RT);
  // pass 2 (cols): xg = RT @ Wih^T + b ; recurrent -> Sb (NHWC layout)
  k_xg_gemm<<<dim3(256, 8), 256, 0, stream>>>(RT, wihc, biasc, XG);
  k_lstm_rec<<<dim3(32, 2), 512, 0, stream>>>(XG, Whh_f, Whh_b, Sb);

  // x_site = double_conv(concat([S,S])) with folded first conv
  k_conv3_v2<<<dim3(256,2), 256, 0, stream>>>(Sb, nullptr, w1f, c2_g1, c2_b1,
                                              nullptr, D1, 256, 256, 0);      // T1
  k_conv3_v2<<<dim3(256,2), 256, 0, stream>>>(D1, nullptr, w2r, c2_g2, c2_b2,
                                              nullptr, D2, 256, 256, 0);      // XS
  // x = double_conv(concat([S, XS]))
  k_conv3_v2<<<dim3(256,2), 256, 0, stream>>>(Sb, D2, w1full, c2_g1, c2_b1,
                                              nullptr, D2b, 512, 256, 0);     // T2
  k_conv3_v2<<<dim3(256,2), 256, 0, stream>>>(D2b, nullptr, w2r, c2_g2, c2_b2,
                                              nullptr, D1, 256, 256, 0);      // Y
  // final double_conv (cv); last conv writes fp32 NCHW to d_out
  k_conv3_v2<<<dim3(256,1), 256, 0, stream>>>(D1, nullptr, wv1, cv_g1, cv_b1,
                                              nullptr, D2, 256, 128, 0);      // Z
  k_conv3_v2<<<dim3(256,1), 256, 0, stream>>>(D2, nullptr, wv2, cv_g2, cv_b2,
                                              (float*)d_out, nullptr, 128, 128, 1);
}

// Round 9
// 721.027 us; speedup vs baseline: 1.0187x; 1.0187x over previous
//
#include <hip/hip_runtime.h>
#include <hip/hip_bf16.h>
#include <math.h>

typedef __bf16 bf16x8 __attribute__((ext_vector_type(8)));
typedef float  f32x4  __attribute__((ext_vector_type(4)));

__device__ __forceinline__ float sigm(float x)  { return 1.f/(1.f+__expf(-x)); }
__device__ __forceinline__ float tanh_f(float x){ return 2.f/(1.f+__expf(-2.f*x)) - 1.f; }
__device__ __forceinline__ float b2f(unsigned short u){
  unsigned int x = ((unsigned int)u) << 16; return __uint_as_float(x);
}
__device__ __forceinline__ unsigned short f2b(float v){
  __hip_bfloat16 h = __float2bfloat16(v); return *(unsigned short*)&h;
}
__device__ __forceinline__ void glds16(const void* g, void* l) {
  __builtin_amdgcn_global_load_lds(
      (const __attribute__((address_space(1))) unsigned int*)g,
      (__attribute__((address_space(3))) unsigned int*)l, 16, 0, 0);
}
__device__ __forceinline__ bf16x8 bzero() {
  bf16x8 v;
  #pragma unroll
  for (int i = 0; i < 8; ++i) v[i] = (__bf16)0.0f;
  return v;
}
// barrier with LDS-only ordering: skip the vmcnt(0) drain __syncthreads would emit.
__device__ __forceinline__ void barrier_lds() {
  asm volatile("s_waitcnt lgkmcnt(0)\n\ts_barrier" ::: "memory");
}

// ---------------- upsample(2x, align_corners) + channel concat -> NHWC bf16 --------------
__global__ __launch_bounds__(256) void k_upcat(const float* __restrict__ x1,
                                               const float* __restrict__ x2,
                                               __hip_bfloat16* __restrict__ X0) {
  int idx = blockIdx.x*256 + threadIdx.x;
  int c = idx & 255;
  int w = (idx >> 8) & 63;
  int h = (idx >> 14) & 63;
  int n = idx >> 20;
  float v;
  if (c < 128) {
    v = x2[((n*128 + c)*64 + h)*64 + w];
  } else {
    int cc = c - 128;
    float py = (h*31.0f)/63.0f;
    int ly = (int)py; int hy = min(ly+1, 31); float fy = py - (float)ly;
    float px = (w*31.0f)/63.0f;
    int lx = (int)px; int hx = min(lx+1, 31); float fx = px - (float)lx;
    const float* p = x1 + (size_t)(n*128 + cc)*1024;
    float v00 = p[ly*32+lx], v01 = p[ly*32+hx];
    float v10 = p[hy*32+lx], v11 = p[hy*32+hx];
    v = (1.f-fy)*((1.f-fx)*v00 + fx*v01) + fy*((1.f-fx)*v10 + fx*v11);
  }
  X0[idx] = __float2bfloat16(v);
}

// ---------------- Wih concat -> bf16 [1024][256]; biasc[1024] = bih+bhh ------------------
__global__ __launch_bounds__(256) void k_wih_prep(
    const float* __restrict__ Wf, const float* __restrict__ Wb,
    const float* __restrict__ bif, const float* __restrict__ bhf,
    const float* __restrict__ bib, const float* __restrict__ bhb,
    __hip_bfloat16* __restrict__ wihc, float* __restrict__ biasc) {
  int idx = blockIdx.x*256 + threadIdx.x;     // 1024*256
  int n = idx >> 8, k = idx & 255;
  float v = (n < 512) ? Wf[n*256 + k] : Wb[(n-512)*256 + k];
  wihc[idx] = __float2bfloat16(v);
  if (idx < 1024) biasc[idx] = (idx < 512) ? bif[idx] + bhf[idx]
                                           : bib[idx-512] + bhb[idx-512];
}

// ---------------- xg GEMM -> xg[dir][t][g][sb32][u128][s16] bf16 (seq-tiled) -------------
__global__ __launch_bounds__(256) void k_xg_gemm(
    const __hip_bfloat16* __restrict__ Xin,
    const __hip_bfloat16* __restrict__ Wihc,
    const float* __restrict__ biasc,
    __hip_bfloat16* __restrict__ xg) {
  __shared__ __align__(16) unsigned short sa[128][72];
  __shared__ __align__(16) unsigned short sw[128][72];
  int bx = blockIdx.x;                 // 256: t = bx>>2, seq0 = (bx&3)*128
  int t = bx >> 2, seq0 = (bx & 3) << 7;
  int n0 = blockIdx.y << 7;
  int tid = threadIdx.x, lane = tid & 63, wid = tid >> 6;
  int wm = wid >> 1, wn = wid & 1;
  int l15 = lane & 15, quad = lane >> 4;
  f32x4 acc[4][4];
  #pragma unroll
  for (int i = 0; i < 4; ++i)
    #pragma unroll
    for (int j = 0; j < 4; ++j) acc[i][j] = (f32x4){0.f,0.f,0.f,0.f};

  for (int k0 = 0; k0 < 256; k0 += 64) {
    __syncthreads();
    for (int idx = tid; idx < 2048; idx += 256) {
      int row = idx >> 4, c4 = (idx & 15) << 2;
      *(ushort4*)&sa[row][c4] = *(const ushort4*)((const unsigned short*)Xin +
          (size_t)((seq0 + row)*64 + t)*256 + k0 + c4);
      *(ushort4*)&sw[row][c4] = *(const ushort4*)((const unsigned short*)Wihc +
          (size_t)(n0 + row)*256 + k0 + c4);
    }
    __syncthreads();
    #pragma unroll
    for (int k32 = 0; k32 < 64; k32 += 32) {
      bf16x8 af[4], bfr[4];
      #pragma unroll
      for (int mt = 0; mt < 4; ++mt)
        af[mt] = *(const bf16x8*)&sa[wm*64 + mt*16 + l15][k32 + quad*8];
      #pragma unroll
      for (int nt = 0; nt < 4; ++nt)
        bfr[nt] = *(const bf16x8*)&sw[wn*64 + nt*16 + l15][k32 + quad*8];
      #pragma unroll
      for (int mt = 0; mt < 4; ++mt)
        #pragma unroll
        for (int nt = 0; nt < 4; ++nt)
          acc[mt][nt] = __builtin_amdgcn_mfma_f32_16x16x32_bf16(
              af[mt], bfr[nt], acc[mt][nt], 0, 0, 0);
    }
  }
  // epilogue: + bias, bf16, seq-tiled store: s16 = quad*4, so each wave's 64 lanes
  // write one contiguous 512B segment per (nt,mt) — fully coalesced.
  #pragma unroll
  for (int nt = 0; nt < 4; ++nt) {
    int cg = n0 + wn*64 + nt*16 + l15;        // gate col incl dir
    int dir = cg >> 9;
    int g   = (cg >> 7) & 3;
    int u   = cg & 127;
    float bias = biasc[cg];
    #pragma unroll
    for (int mt = 0; mt < 4; ++mt) {
      int sbt = (seq0 + wm*64 + mt*16) >> 4;  // seq tile 0..31
      unsigned short* op = (unsigned short*)xg +
          (((((size_t)(dir*64 + t)*4 + g)*32 + sbt)*128 + u) << 4) + quad*4;
      f32x4 a = acc[mt][nt];
      ushort4 o;
      o.x = f2b(a[0] + bias); o.y = f2b(a[1] + bias);
      o.z = f2b(a[2] + bias); o.w = f2b(a[3] + bias);
      *(ushort4*)op = o;
    }
  }
}

// ---------------- recurrent LSTM core v5b: 16 seqs/block, cell-aligned gates, tiled xg ---
// grid (32, 2), 512 threads. Wave w's 4 N-tiles = the 4 gate planes of units 16w..16w+15:
// each lane holds I,F,G,O for its 4 (unit, seq) cells in-register. xg loads are
// contiguous 512B per wave per gate (seq-tiled layout) and seed the MFMA C operand.
__global__ __launch_bounds__(512, 1) void k_lstm_rec(
    const __hip_bfloat16* __restrict__ xg,
    const float* __restrict__ WhhF, const float* __restrict__ WhhB,
    __hip_bfloat16* __restrict__ out) {
  const int dir = blockIdx.y;
  const int sb  = blockIdx.x;               // seq tile: seqs sb*16 .. +16
  const float* Whh = dir ? WhhB : WhhF;
  __shared__ __align__(16) unsigned short hs[2][16][132];  // [buf][seq][unit]
  const int tid = threadIdx.x, lane = tid & 63, w = tid >> 6;   // wave 0..7
  const int l15 = lane & 15, quad = lane >> 4;
  const int u = w*16 + l15;                 // unit this lane owns (all 4 gate planes)

  // Whh fragments: wf[g][kc] = B[k=kc*32+quad*8..+8][gate g*128+u]
  bf16x8 wf[4][4];
  #pragma unroll
  for (int g = 0; g < 4; ++g)
    #pragma unroll
    for (int kc = 0; kc < 4; ++kc) {
      const float* wp = Whh + (size_t)(g*128 + u)*128 + kc*32 + quad*8;
      float4 w0 = *(const float4*)wp;
      float4 w1 = *(const float4*)(wp + 4);
      bf16x8 f;
      f[0]=(__bf16)w0.x; f[1]=(__bf16)w0.y; f[2]=(__bf16)w0.z; f[3]=(__bf16)w0.w;
      f[4]=(__bf16)w1.x; f[5]=(__bf16)w1.y; f[6]=(__bf16)w1.z; f[7]=(__bf16)w1.w;
      wf[g][kc] = f;
    }
  for (int i = tid; i < 2*16*132; i += 512) ((unsigned short*)hs)[i] = 0;

  float cst[4] = {0.f, 0.f, 0.f, 0.f};      // c for (u, seqs quad*4+0..3)

  // xg base for this (dir, sb, u, quad): index = ((((dir*64+t)*4+g)*32+sb)*128+u)*16+quad*4
  const unsigned short* xp = (const unsigned short*)xg +
      (((size_t)sb*128 + u) << 4) + quad*4;
  const size_t dbase = (size_t)dir*64*4*32*128*16;
  ushort4 xv[4], xn[4];
  #define LDX(stp, dst)                                                        \
    {                                                                          \
      int ts_ = (stp) < 64 ? (stp) : 63;                                       \
      int t_  = dir ? 63 - ts_ : ts_;                                          \
      _Pragma("unroll")                                                        \
      for (int g_ = 0; g_ < 4; ++g_)                                           \
        dst[g_] = *(const ushort4*)(xp + dbase +                               \
            (((size_t)(t_*4 + g_)*32) << 11));                                 \
    }
  LDX(0, xv);
  __syncthreads();                          // hs init visible

  for (int step = 0; step < 64; ++step) {
    int t = dir ? 63 - step : step;
    int p = step & 1;                       // read buffer
    // A-frags from h(t-1): A[m=l15 seq][k=kc*32+quad*8+j unit]
    bf16x8 af[4];
    #pragma unroll
    for (int kc = 0; kc < 4; ++kc)
      af[kc] = *(const bf16x8*)&hs[p][l15][kc*32 + quad*8];
    // C init = xg pre-activations (bias folded in by the GEMM)
    f32x4 acc[4];
    #pragma unroll
    for (int g = 0; g < 4; ++g) {
      acc[g][0] = b2f(xv[g].x); acc[g][1] = b2f(xv[g].y);
      acc[g][2] = b2f(xv[g].z); acc[g][3] = b2f(xv[g].w);
    }
    LDX(step + 1, xn);                      // prefetch next step
    #pragma unroll
    for (int kc = 0; kc < 4; ++kc)
      #pragma unroll
      for (int g = 0; g < 4; ++g)
        acc[g] = __builtin_amdgcn_mfma_f32_16x16x32_bf16(
            af[kc], wf[g][kc], acc[g], 0, 0, 0);
    // nonlinearity fully in-register: 4 cells (unit u, seqs quad*4+r)
    #pragma unroll
    for (int r = 0; r < 4; ++r) {
      float I = acc[0][r], F = acc[1][r], G = acc[2][r], O = acc[3][r];
      float cv = sigm(F)*cst[r] + sigm(I)*tanh_f(G);
      float hv = sigm(O)*tanh_f(cv);
      cst[r] = cv;
      unsigned short hb = f2b(hv);
      hs[1 - p][quad*4 + r][u] = hb;
      int gs = sb*16 + quad*4 + r;
      ((unsigned short*)out)[(size_t)(((gs >> 6)*64 + t)*64 + (gs & 63))*256
                             + dir*128 + u] = hb;
    }
    barrier_lds();                          // h(t) visible; WAR on hs[p] resolved
    #pragma unroll
    for (int g = 0; g < 4; ++g) xv[g] = xn[g];
  }
  #undef LDX
}

// ---------------- weight reformat OIHW fp32 -> (ky,kx,co,ci) bf16, optional fold ---------
__global__ __launch_bounds__(256) void k_wrefmt_bf16(const float* __restrict__ src,
                                                     __hip_bfloat16* __restrict__ dst,
                                                     int Ci, int Co, int fold) {
  int idx = blockIdx.x*256 + threadIdx.x;
  int total = 9*Ci*Co;
  if (idx >= total) return;
  int ci = idx % Ci;
  int co = (idx / Ci) % Co;
  int k  = idx / (Ci*Co);             // ky*3+kx
  int CiS = fold ? Ci*2 : Ci;
  float v = src[(size_t)(co*CiS + ci)*9 + k];
  if (fold) v += src[(size_t)(co*CiS + ci + Ci)*9 + k];
  dst[idx] = __float2bfloat16(v);
}

// ---------------- conv3x3 SAME + BN + ReLU, bf16 MFMA, async glds pipeline ---------------
__global__ __launch_bounds__(256, 2) void k_conv3_v2(
    const __hip_bfloat16* __restrict__ inA, const __hip_bfloat16* __restrict__ inB,
    const __hip_bfloat16* __restrict__ wgt,
    const float* __restrict__ gam, const float* __restrict__ bet,
    float* __restrict__ outF, __hip_bfloat16* __restrict__ outB,
    int Cin, int Co, int nchw) {
  __shared__ __align__(16) unsigned short si[2][64][64];   // 16 KB
  __shared__ __align__(16) unsigned short sw[3][128][64];  // 48 KB
  int bx = blockIdx.x;
  int n  = bx >> 5;
  int h0 = (bx & 31) << 1;
  int co0 = blockIdx.y << 7;
  int tid = threadIdx.x;
  int lane = tid & 63;
  int wid  = tid >> 6;
  int wm = wid >> 1;
  int wn = wid & 1;
  int l15 = lane & 15, quad = lane >> 4;

  f32x4 acc[4][4];
  #pragma unroll
  for (int i = 0; i < 4; ++i)
    #pragma unroll
    for (int j = 0; j < 4; ++j) acc[i][j] = (f32x4){0.f,0.f,0.f,0.f};

  int cs = inB ? 256 : Cin;
  for (int ky = 0; ky < 3; ++ky) {
    for (int ci0 = 0; ci0 < Cin; ci0 += 64) {
      const unsigned short* src = (const unsigned short*)inA; int cb = ci0;
      if (inB && ci0 >= 256) { src = (const unsigned short*)inB; cb = ci0 - 256; }
      __syncthreads();
      {
        int r = wid >> 1;
        int ih = h0 + r + ky - 1;
        int half = (wid & 1) << 5;
        if (ih >= 0 && ih <= 63) {
          const unsigned short* gsrc = src + (size_t)((n*64 + ih)*64)*cs + cb;
          int pl = lane >> 3, pc = lane & 7;
          #pragma unroll
          for (int q = 0; q < 4; ++q) {
            int iw = half + q*8 + pl;
            int lc = pc ^ (iw & 7);
            glds16(gsrc + (size_t)iw*cs + lc*8, &si[r][half + q*8][0]);
          }
        } else {
          uint4 z = {0,0,0,0};
          #pragma unroll
          for (int q = 0; q < 4; ++q)
            *(uint4*)(&si[r][half + q*8][0] + lane*8) = z;
        }
      }
      {
        int col = lane >> 3, pc = lane & 7;
        const unsigned short* wk = (const unsigned short*)wgt +
            (size_t)(ky*3*Co + co0)*Cin + ci0;
        #pragma unroll
        for (int j = 0; j < 12; ++j) {
          int s = wid + j*4;
          int kx = s >> 4, co8 = (s & 15) << 3;
          int co = co8 + col;
          int lc = pc ^ (co & 7);
          glds16(wk + (size_t)(kx*Co + co)*Cin + lc*8, &sw[kx][co8][0]);
        }
      }
      __syncthreads();
      #pragma unroll
      for (int kx = 0; kx < 3; ++kx) {
        #pragma unroll
        for (int k32 = 0; k32 < 2; ++k32) {
          bf16x8 af[4], bfr[4];
          #pragma unroll
          for (int mt = 0; mt < 4; ++mt) {
            int iw = mt*16 + l15 + kx - 1;
            int iwc = iw & 63;
            int pc = (k32*4 + quad) ^ (iwc & 7);
            af[mt] = *(const bf16x8*)&si[wm][iwc][pc*8];
            if ((kx == 0 && mt == 0 && l15 == 0) ||
                (kx == 2 && mt == 3 && l15 == 15))
              af[mt] = bzero();
          }
          #pragma unroll
          for (int nt = 0; nt < 4; ++nt) {
            int co = wn*64 + nt*16 + l15;
            int pc = (k32*4 + quad) ^ (co & 7);
            bfr[nt] = *(const bf16x8*)&sw[kx][co][pc*8];
          }
          #pragma unroll
          for (int mt = 0; mt < 4; ++mt)
            #pragma unroll
            for (int nt = 0; nt < 4; ++nt)
              acc[mt][nt] = __builtin_amdgcn_mfma_f32_16x16x32_bf16(
                  af[mt], bfr[nt], acc[mt][nt], 0, 0, 0);
        }
      }
    }
  }
  const float kS = 0.9999950000374997f;   // 1/sqrt(1+1e-5)
  int h = h0 + wm;
  #pragma unroll
  for (int nt = 0; nt < 4; ++nt) {
    int co = co0 + wn*64 + nt*16 + l15;
    float scale = gam[co]*kS, bb = bet[co];
    #pragma unroll
    for (int mt = 0; mt < 4; ++mt) {
      f32x4 a = acc[mt][nt];
      #pragma unroll
      for (int r = 0; r < 4; ++r) {
        int w = mt*16 + quad*4 + r;
        float v = fmaf(a[r], scale, bb);
        v = v > 0.f ? v : 0.f;
        if (nchw) outF[(size_t)((n*Co + co)*64 + h)*64 + w] = v;
        else      outB[(size_t)((n*64 + h)*64 + w)*Co + co] = __float2bfloat16(v);
      }
    }
  }
}

extern "C" void kernel_launch(void* const* d_in, const int* in_sizes, int n_in,
                              void* d_out, int out_size, void* d_ws, size_t ws_size,
                              hipStream_t stream) {
  const float* x1    = (const float*)d_in[0];
  const float* x2    = (const float*)d_in[1];
  const float* Wih_f = (const float*)d_in[2];
  const float* Whh_f = (const float*)d_in[3];
  const float* bih_f = (const float*)d_in[4];
  const float* bhh_f = (const float*)d_in[5];
  const float* Wih_b = (const float*)d_in[6];
  const float* Whh_b = (const float*)d_in[7];
  const float* bih_b = (const float*)d_in[8];
  const float* bhh_b = (const float*)d_in[9];
  const float* c2_w1 = (const float*)d_in[10];
  const float* c2_g1 = (const float*)d_in[11];
  const float* c2_b1 = (const float*)d_in[12];
  const float* c2_w2 = (const float*)d_in[13];
  const float* c2_g2 = (const float*)d_in[14];
  const float* c2_b2 = (const float*)d_in[15];
  const float* cv_w1 = (const float*)d_in[16];
  const float* cv_g1 = (const float*)d_in[17];
  const float* cv_b1 = (const float*)d_in[18];
  const float* cv_w2 = (const float*)d_in[19];
  const float* cv_g2 = (const float*)d_in[20];
  const float* cv_b2 = (const float*)d_in[21];

  // ---- workspace layout (~107 MB, aliased) ----
  char* base = (char*)d_ws;
  const size_t SLOTB = 16777216ull;                 // bf16 activation slot
  __hip_bfloat16* Xb  = (__hip_bfloat16*)(base);
  __hip_bfloat16* Sb  = (__hip_bfloat16*)(base);
  __hip_bfloat16* XG  = (__hip_bfloat16*)(base + SLOTB);
  __hip_bfloat16* D2  = (__hip_bfloat16*)(base + SLOTB);
  __hip_bfloat16* D2b = (__hip_bfloat16*)(base + 2*SLOTB);
  __hip_bfloat16* RT  = (__hip_bfloat16*)(base + SLOTB + 67108864ull);
  __hip_bfloat16* D1  = RT;
  char* wq = base + SLOTB + 67108864ull + SLOTB;
  __hip_bfloat16* wihc  = (__hip_bfloat16*)wq;
  float*          biasc = (float*)(wq + 524288);
  char* cw = wq + 528384;
  __hip_bfloat16* w1f    = (__hip_bfloat16*)(cw);
  __hip_bfloat16* w1full = (__hip_bfloat16*)(cw + 1179648);
  __hip_bfloat16* w2r    = (__hip_bfloat16*)(cw + 3538944);
  __hip_bfloat16* wv1    = (__hip_bfloat16*)(cw + 4718592);
  __hip_bfloat16* wv2    = (__hip_bfloat16*)(cw + 5308416);

  // weight prep
  k_wih_prep<<<1024, 256, 0, stream>>>(Wih_f, Wih_b, bih_f, bhh_f, bih_b, bhh_b,
                                       wihc, biasc);
  k_wrefmt_bf16<<<(9*256*256+255)/256, 256, 0, stream>>>(c2_w1, w1f,    256, 256, 1);
  k_wrefmt_bf16<<<(9*512*256+255)/256, 256, 0, stream>>>(c2_w1, w1full, 512, 256, 0);
  k_wrefmt_bf16<<<(9*256*256+255)/256, 256, 0, stream>>>(c2_w2, w2r,    256, 256, 0);
  k_wrefmt_bf16<<<(9*256*128+255)/256, 256, 0, stream>>>(cv_w1, wv1,    256, 128, 0);
  k_wrefmt_bf16<<<(9*128*128+255)/256, 256, 0, stream>>>(cv_w2, wv2,    128, 128, 0);

  // upsample + concat -> Xb (NHWC bf16)
  k_upcat<<<32768, 256, 0, stream>>>(x1, x2, Xb);

  // pass 1 (rows): xg = Xb @ Wih^T + b ; recurrent -> RT (transposed layout)
  k_xg_gemm<<<dim3(256, 8), 256, 0, stream>>>(Xb, wihc, biasc, XG);
  k_lstm_rec<<<dim3(32, 2), 512, 0, stream>>>(XG, Whh_f, Whh_b, RT);
  // pass 2 (cols): xg = RT @ Wih^T + b ; recurrent -> Sb (NHWC layout)
  k_xg_gemm<<<dim3(256, 8), 256, 0, stream>>>(RT, wihc, biasc, XG);
  k_lstm_rec<<<dim3(32, 2), 512, 0, stream>>>(XG, Whh_f, Whh_b, Sb);

  // x_site = double_conv(concat([S,S])) with folded first conv
  k_conv3_v2<<<dim3(256,2), 256, 0, stream>>>(Sb, nullptr, w1f, c2_g1, c2_b1,
                                              nullptr, D1, 256, 256, 0);      // T1
  k_conv3_v2<<<dim3(256,2), 256, 0, stream>>>(D1, nullptr, w2r, c2_g2, c2_b2,
                                              nullptr, D2, 256, 256, 0);      // XS
  // x = double_conv(concat([S, XS]))
  k_conv3_v2<<<dim3(256,2), 256, 0, stream>>>(Sb, D2, w1full, c2_g1, c2_b1,
                                              nullptr, D2b, 512, 256, 0);     // T2
  k_conv3_v2<<<dim3(256,2), 256, 0, stream>>>(D2b, nullptr, w2r, c2_g2, c2_b2,
                                              nullptr, D1, 256, 256, 0);      // Y
  // final double_conv (cv); last conv writes fp32 NCHW to d_out
  k_conv3_v2<<<dim3(256,1), 256, 0, stream>>>(D1, nullptr, wv1, cv_g1, cv_b1,
                                              nullptr, D2, 256, 128, 0);      // Z
  k_conv3_v2<<<dim3(256,1), 256, 0, stream>>>(D2, nullptr, wv2, cv_g2, cv_b2,
                                              (float*)d_out, nullptr, 128, 128, 1);
}

// Round 10
// 659.600 us; speedup vs baseline: 1.1136x; 1.0931x over previous
//
#include <hip/hip_runtime.h>
#include <hip/hip_bf16.h>
#include <math.h>

typedef __bf16 bf16x8 __attribute__((ext_vector_type(8)));
typedef float  f32x4  __attribute__((ext_vector_type(4)));

__device__ __forceinline__ float sigm(float x)  { return 1.f/(1.f+__expf(-x)); }
__device__ __forceinline__ float tanh_f(float x){ return 2.f/(1.f+__expf(-2.f*x)) - 1.f; }
__device__ __forceinline__ float b2f(unsigned short u){
  unsigned int x = ((unsigned int)u) << 16; return __uint_as_float(x);
}
__device__ __forceinline__ unsigned short f2b(float v){
  __hip_bfloat16 h = __float2bfloat16(v); return *(unsigned short*)&h;
}
__device__ __forceinline__ void glds16(const void* g, void* l) {
  __builtin_amdgcn_global_load_lds(
      (const __attribute__((address_space(1))) unsigned int*)g,
      (__attribute__((address_space(3))) unsigned int*)l, 16, 0, 0);
}
__device__ __forceinline__ bf16x8 bzero() {
  bf16x8 v;
  #pragma unroll
  for (int i = 0; i < 8; ++i) v[i] = (__bf16)0.0f;
  return v;
}
// barrier with LDS-only ordering (safe when global ops around it are thread-private)
__device__ __forceinline__ void barrier_lds() {
  asm volatile("s_waitcnt lgkmcnt(0)\n\ts_barrier" ::: "memory");
}

// ---------------- upsample(2x, align_corners) + channel concat -> NHWC bf16 --------------
__global__ __launch_bounds__(256) void k_upcat(const float* __restrict__ x1,
                                               const float* __restrict__ x2,
                                               __hip_bfloat16* __restrict__ X0) {
  int idx = blockIdx.x*256 + threadIdx.x;
  int c = idx & 255;
  int w = (idx >> 8) & 63;
  int h = (idx >> 14) & 63;
  int n = idx >> 20;
  float v;
  if (c < 128) {
    v = x2[((n*128 + c)*64 + h)*64 + w];
  } else {
    int cc = c - 128;
    float py = (h*31.0f)/63.0f;
    int ly = (int)py; int hy = min(ly+1, 31); float fy = py - (float)ly;
    float px = (w*31.0f)/63.0f;
    int lx = (int)px; int hx = min(lx+1, 31); float fx = px - (float)lx;
    const float* p = x1 + (size_t)(n*128 + cc)*1024;
    float v00 = p[ly*32+lx], v01 = p[ly*32+hx];
    float v10 = p[hy*32+lx], v11 = p[hy*32+hx];
    v = (1.f-fy)*((1.f-fx)*v00 + fx*v01) + fy*((1.f-fx)*v10 + fx*v11);
  }
  X0[idx] = __float2bfloat16(v);
}

// ---------------- Wih concat -> bf16 [1024][256]; biasc[1024] = bih+bhh ------------------
__global__ __launch_bounds__(256) void k_wih_prep(
    const float* __restrict__ Wf, const float* __restrict__ Wb,
    const float* __restrict__ bif, const float* __restrict__ bhf,
    const float* __restrict__ bib, const float* __restrict__ bhb,
    __hip_bfloat16* __restrict__ wihc, float* __restrict__ biasc) {
  int idx = blockIdx.x*256 + threadIdx.x;     // 1024*256
  int n = idx >> 8, k = idx & 255;
  float v = (n < 512) ? Wf[n*256 + k] : Wb[(n-512)*256 + k];
  wihc[idx] = __float2bfloat16(v);
  if (idx < 1024) biasc[idx] = (idx < 512) ? bif[idx] + bhf[idx]
                                           : bib[idx-512] + bhb[idx-512];
}

// ---------------- xg GEMM -> xg[dir][t][g][s][u] bf16 (planar, round-6 version) ----------
__global__ __launch_bounds__(256) void k_xg_gemm(
    const __hip_bfloat16* __restrict__ Xin,
    const __hip_bfloat16* __restrict__ Wihc,
    const float* __restrict__ biasc,
    __hip_bfloat16* __restrict__ xg) {
  __shared__ __align__(16) unsigned short sa[128][72];
  __shared__ __align__(16) unsigned short sw[128][72];
  int bx = blockIdx.x;                 // 256: t = bx>>2, seq0 = (bx&3)*128
  int t = bx >> 2, seq0 = (bx & 3) << 7;
  int n0 = blockIdx.y << 7;
  int tid = threadIdx.x, lane = tid & 63, wid = tid >> 6;
  int wm = wid >> 1, wn = wid & 1;
  int l15 = lane & 15, quad = lane >> 4;
  f32x4 acc[4][4];
  #pragma unroll
  for (int i = 0; i < 4; ++i)
    #pragma unroll
    for (int j = 0; j < 4; ++j) acc[i][j] = (f32x4){0.f,0.f,0.f,0.f};

  for (int k0 = 0; k0 < 256; k0 += 64) {
    __syncthreads();
    for (int idx = tid; idx < 2048; idx += 256) {
      int row = idx >> 4, c4 = (idx & 15) << 2;
      *(ushort4*)&sa[row][c4] = *(const ushort4*)((const unsigned short*)Xin +
          (size_t)((seq0 + row)*64 + t)*256 + k0 + c4);
      *(ushort4*)&sw[row][c4] = *(const ushort4*)((const unsigned short*)Wihc +
          (size_t)(n0 + row)*256 + k0 + c4);
    }
    __syncthreads();
    #pragma unroll
    for (int k32 = 0; k32 < 64; k32 += 32) {
      bf16x8 af[4], bfr[4];
      #pragma unroll
      for (int mt = 0; mt < 4; ++mt)
        af[mt] = *(const bf16x8*)&sa[wm*64 + mt*16 + l15][k32 + quad*8];
      #pragma unroll
      for (int nt = 0; nt < 4; ++nt)
        bfr[nt] = *(const bf16x8*)&sw[wn*64 + nt*16 + l15][k32 + quad*8];
      #pragma unroll
      for (int mt = 0; mt < 4; ++mt)
        #pragma unroll
        for (int nt = 0; nt < 4; ++nt)
          acc[mt][nt] = __builtin_amdgcn_mfma_f32_16x16x32_bf16(
              af[mt], bfr[nt], acc[mt][nt], 0, 0, 0);
    }
  }
  // epilogue: + bias, bf16, planar store [dir][t][g][s][u]
  #pragma unroll
  for (int nt = 0; nt < 4; ++nt) {
    int cg = n0 + wn*64 + nt*16 + l15;        // gate col incl dir
    int dir = cg >> 9;
    int g   = (cg >> 7) & 3;
    int u   = cg & 127;
    float bias = biasc[cg];
    unsigned short* op = (unsigned short*)xg +
        (size_t)(((dir*64 + t)*4 + g)*512)*128 + u;
    #pragma unroll
    for (int mt = 0; mt < 4; ++mt) {
      int sbase = seq0 + wm*64 + mt*16 + quad*4;
      f32x4 a = acc[mt][nt];
      #pragma unroll
      for (int r = 0; r < 4; ++r)
        op[(size_t)(sbase + r)*128] = f2b(a[r] + bias);
    }
  }
}

// ---------------- recurrent LSTM core v3 (round-6, best measured: 84 us) -----------------
// grid (128, 2), 256 thr. 4 seqs/block, 256 blocks (full GPU). Whh in VGPRs; h in LDS
// rows 0-3; gate pre-activations redistributed via gv LDS (2 cells/thread nonlinearity).
__global__ __launch_bounds__(256, 1) void k_lstm_rec(
    const __hip_bfloat16* __restrict__ xg,
    const float* __restrict__ WhhF, const float* __restrict__ WhhB,
    __hip_bfloat16* __restrict__ out) {
  const int dir = blockIdx.y;
  const int sb  = blockIdx.x;               // seqs sb*4 .. +4
  const float* Whh = dir ? WhhB : WhhF;
  __shared__ __align__(16) unsigned short hs[16][136];   // rows 4-15 stay zero
  __shared__ __align__(16) float gv[4][128][4];          // [s][u][IFGO] 8KB
  const int tid = threadIdx.x, lane = tid & 63, wv = tid >> 6;
  const int l15 = lane & 15, quad = lane >> 4;

  bf16x8 wf[4][2][4];
  #pragma unroll
  for (int g = 0; g < 4; ++g)
    #pragma unroll
    for (int ut = 0; ut < 2; ++ut) {
      int gate = g*128 + wv*32 + ut*16 + l15;
      #pragma unroll
      for (int kc = 0; kc < 4; ++kc) {
        const float* wp = Whh + (size_t)gate*128 + kc*32 + quad*8;
        float4 w0 = *(const float4*)wp;
        float4 w1 = *(const float4*)(wp + 4);
        bf16x8 f;
        f[0]=(__bf16)w0.x; f[1]=(__bf16)w0.y; f[2]=(__bf16)w0.z; f[3]=(__bf16)w0.w;
        f[4]=(__bf16)w1.x; f[5]=(__bf16)w1.y; f[6]=(__bf16)w1.z; f[7]=(__bf16)w1.w;
        wf[g][ut][kc] = f;
      }
    }
  for (int i = tid; i < 16*136; i += 256) ((unsigned short*)hs)[i] = 0;

  const int u_  = tid & 127;
  const int s0_ = tid >> 7;
  float cst[2] = {0.f, 0.f};

  const unsigned short* xp = (const unsigned short*)xg +
      (size_t)dir*64*4*512*128;
  unsigned short xv[2][4], xn[2][4];
  #define LDX(stp, dst)                                                    \
    {                                                                      \
      int ts_ = (stp) < 64 ? (stp) : 63;                                   \
      int t_  = dir ? 63 - ts_ : ts_;                                      \
      _Pragma("unroll")                                                    \
      for (int j_ = 0; j_ < 2; ++j_) {                                     \
        int s_ = s0_ + j_*2;                                               \
        _Pragma("unroll")                                                  \
        for (int g_ = 0; g_ < 4; ++g_)                                     \
          dst[j_][g_] = xp[(size_t)((t_*4 + g_)*512 + sb*4 + s_)*128 + u_];\
      }                                                                    \
    }
  LDX(0, xv);
  __syncthreads();                          // hs init visible

  for (int step = 0; step < 64; ++step) {
    int t = dir ? 63 - step : step;
    LDX(step + 1, xn);                      // prefetch (used next step)
    bf16x8 af[2][4];
    #pragma unroll
    for (int mt = 0; mt < 2; ++mt)
      #pragma unroll
      for (int kc = 0; kc < 4; ++kc)
        af[mt][kc] = *(const bf16x8*)&hs[mt*16 + l15][kc*32 + quad*8];
    f32x4 acc[2][4][2];
    #pragma unroll
    for (int mt = 0; mt < 2; ++mt)
      #pragma unroll
      for (int g = 0; g < 4; ++g)
        #pragma unroll
        for (int ut = 0; ut < 2; ++ut) acc[mt][g][ut] = (f32x4){0.f,0.f,0.f,0.f};
    #pragma unroll
    for (int kc = 0; kc < 4; ++kc)
      #pragma unroll
      for (int mt = 0; mt < 2; ++mt)
        #pragma unroll
        for (int g = 0; g < 4; ++g)
          #pragma unroll
          for (int ut = 0; ut < 2; ++ut)
            acc[mt][g][ut] = __builtin_amdgcn_mfma_f32_16x16x32_bf16(
                af[mt][kc], wf[g][ut][kc], acc[mt][g][ut], 0, 0, 0);
    // scatter valid rows (0-3 = quad0; mt picks seq pair) to gv as float4{I,F,G,O}
    if (quad == 0) {
      #pragma unroll
      for (int ut = 0; ut < 2; ++ut) {
        int u = wv*32 + ut*16 + l15;
        #pragma unroll
        for (int r = 0; r < 4; ++r) {
          float4 q;
          q.x = acc[0][0][ut][r]; q.y = acc[0][1][ut][r];
          q.z = acc[0][2][ut][r]; q.w = acc[0][3][ut][r];
          *(float4*)&gv[r][u][0] = q;
        }
      }
    }
    barrier_lds();                          // gv ready
    #pragma unroll
    for (int j = 0; j < 2; ++j) {
      int s = s0_ + j*2;
      float4 gq = *(const float4*)&gv[s][u_][0];
      float I = gq.x + b2f(xv[j][0]);
      float F = gq.y + b2f(xv[j][1]);
      float G = gq.z + b2f(xv[j][2]);
      float O = gq.w + b2f(xv[j][3]);
      float cv = sigm(F)*cst[j] + sigm(I)*tanh_f(G);
      float hv = sigm(O)*tanh_f(cv);
      cst[j] = cv;
      unsigned short hb = f2b(hv);
      hs[s][u_] = hb;
      int gs = sb*4 + s;
      ((unsigned short*)out)[(size_t)(((gs >> 6)*64 + t)*64 + (gs & 63))*256
                             + dir*128 + u_] = hb;
    }
    barrier_lds();                          // h(t) ready for next af read
    #pragma unroll
    for (int j = 0; j < 2; ++j)
      #pragma unroll
      for (int g = 0; g < 4; ++g) xv[j][g] = xn[j][g];
  }
  #undef LDX
}

// ---------------- weight reformat OIHW fp32 -> (ky,kx,co,ci) bf16, optional fold ---------
__global__ __launch_bounds__(256) void k_wrefmt_bf16(const float* __restrict__ src,
                                                     __hip_bfloat16* __restrict__ dst,
                                                     int Ci, int Co, int fold) {
  int idx = blockIdx.x*256 + threadIdx.x;
  int total = 9*Ci*Co;
  if (idx >= total) return;
  int ci = idx % Ci;
  int co = (idx / Ci) % Co;
  int k  = idx / (Ci*Co);             // ky*3+kx
  int CiS = fold ? Ci*2 : Ci;
  float v = src[(size_t)(co*CiS + ci)*9 + k];
  if (fold) v += src[(size_t)(co*CiS + ci + Ci)*9 + k];
  dst[idx] = __float2bfloat16(v);
}

// ---------------- conv3x3 v3: M=256 (4 h-rows) x N=64 co, si staged once per ci0 ---------
// block 256 thr, 4 waves; wave wm owns output row h0+wm (M=64 over w). LDS: si[6 rows]
// staged ONCE per ci0 and reused across all 3 ky (halo dedup); sw 24KB per ky.
// 72 KB LDS -> 2 blocks/CU. XOR-swizzled glds placement identical to verified v2.
__global__ __launch_bounds__(256, 2) void k_conv3_v3(
    const __hip_bfloat16* __restrict__ inA, const __hip_bfloat16* __restrict__ inB,
    const __hip_bfloat16* __restrict__ wgt,
    const float* __restrict__ gam, const float* __restrict__ bet,
    float* __restrict__ outF, __hip_bfloat16* __restrict__ outB,
    int Cin, int Co, int nchw) {
  __shared__ __align__(16) unsigned short si[6][64][64];   // 48 KB (rows h0-1..h0+4)
  __shared__ __align__(16) unsigned short sw[3][64][64];   // 24 KB (3 kx x 64 co)
  int bx = blockIdx.x;
  int n  = bx >> 4;
  int h0 = (bx & 15) << 2;
  int co0 = blockIdx.y << 6;
  int tid = threadIdx.x;
  int lane = tid & 63;
  int wvid = tid >> 6;                 // wave 0..3 = output row wm
  int l15 = lane & 15, quad = lane >> 4;
  int pl = lane >> 3, pc = lane & 7;   // staging lane split

  f32x4 acc[4][4];
  #pragma unroll
  for (int i = 0; i < 4; ++i)
    #pragma unroll
    for (int j = 0; j < 4; ++j) acc[i][j] = (f32x4){0.f,0.f,0.f,0.f};

  int cs = inB ? 256 : Cin;
  for (int ci0 = 0; ci0 < Cin; ci0 += 64) {
    const unsigned short* src = (const unsigned short*)inA; int cb = ci0;
    if (inB && ci0 >= 256) { src = (const unsigned short*)inB; cb = ci0 - 256; }
    __syncthreads();                   // previous si/sw fully consumed
    // ---- stage si: 6 rows x 64 px x 64 ci; 48 wave-segments of 1KB, 12 per wave ----
    #pragma unroll
    for (int j = 0; j < 12; ++j) {
      int s = wvid + j*4;              // 0..47
      int row = s >> 3, grp = s & 7;
      int ih = h0 + row - 1;
      if (ih >= 0 && ih <= 63) {
        const unsigned short* gsrc = src + (size_t)((n*64 + ih)*64)*cs + cb;
        int iw = grp*8 + pl;
        int lc = pc ^ (iw & 7);
        glds16(gsrc + (size_t)iw*cs + lc*8, &si[row][grp*8][0]);
      } else {
        uint4 z = {0,0,0,0};
        *(uint4*)((unsigned short*)&si[row][grp*8][0] + lane*8) = z;
      }
    }
    for (int ky = 0; ky < 3; ++ky) {
      if (ky) __syncthreads();         // previous sw consumed
      // ---- stage sw: 3 kx x 64 co x 64 ci; 24 segments, 6 per wave ----
      {
        const unsigned short* wk = (const unsigned short*)wgt +
            (size_t)(ky*3*Co + co0)*Cin + ci0;
        #pragma unroll
        for (int j = 0; j < 6; ++j) {
          int s = wvid + j*4;          // 0..23
          int kx = s >> 3, cg = s & 7;
          int co = cg*8 + pl;
          int lc = pc ^ (co & 7);
          glds16(wk + (size_t)(kx*Co + co)*Cin + lc*8, &sw[kx][cg*8][0]);
        }
      }
      __syncthreads();                 // glds drained
      int row = wvid + ky;             // si row for this wave at this ky
      #pragma unroll
      for (int kx = 0; kx < 3; ++kx) {
        #pragma unroll
        for (int k32 = 0; k32 < 2; ++k32) {
          bf16x8 af[4], bfr[4];
          #pragma unroll
          for (int mt = 0; mt < 4; ++mt) {
            int iw = mt*16 + l15 + kx - 1;
            int iwc = iw & 63;
            int pcc = (k32*4 + quad) ^ (iwc & 7);
            af[mt] = *(const bf16x8*)&si[row][iwc][pcc*8];
            if ((kx == 0 && mt == 0 && l15 == 0) ||
                (kx == 2 && mt == 3 && l15 == 15))
              af[mt] = bzero();        // SAME-padding w-edge taps
          }
          #pragma unroll
          for (int nt = 0; nt < 4; ++nt) {
            int co = nt*16 + l15;
            int pcc = (k32*4 + quad) ^ (co & 7);
            bfr[nt] = *(const bf16x8*)&sw[kx][co][pcc*8];
          }
          #pragma unroll
          for (int mt = 0; mt < 4; ++mt)
            #pragma unroll
            for (int nt = 0; nt < 4; ++nt)
              acc[mt][nt] = __builtin_amdgcn_mfma_f32_16x16x32_bf16(
                  af[mt], bfr[nt], acc[mt][nt], 0, 0, 0);
        }
      }
    }
  }
  // epilogue: BN scale + ReLU; C/D layout col=lane&15, row=quad*4+reg
  const float kS = 0.9999950000374997f;   // 1/sqrt(1+1e-5)
  int h = h0 + wvid;
  #pragma unroll
  for (int nt = 0; nt < 4; ++nt) {
    int co = co0 + nt*16 + l15;
    float scale = gam[co]*kS, bb = bet[co];
    #pragma unroll
    for (int mt = 0; mt < 4; ++mt) {
      f32x4 a = acc[mt][nt];
      #pragma unroll
      for (int r = 0; r < 4; ++r) {
        int w = mt*16 + quad*4 + r;
        float v = fmaf(a[r], scale, bb);
        v = v > 0.f ? v : 0.f;
        if (nchw) outF[(size_t)((n*Co + co)*64 + h)*64 + w] = v;
        else      outB[(size_t)((n*64 + h)*64 + w)*Co + co] = __float2bfloat16(v);
      }
    }
  }
}

extern "C" void kernel_launch(void* const* d_in, const int* in_sizes, int n_in,
                              void* d_out, int out_size, void* d_ws, size_t ws_size,
                              hipStream_t stream) {
  const float* x1    = (const float*)d_in[0];
  const float* x2    = (const float*)d_in[1];
  const float* Wih_f = (const float*)d_in[2];
  const float* Whh_f = (const float*)d_in[3];
  const float* bih_f = (const float*)d_in[4];
  const float* bhh_f = (const float*)d_in[5];
  const float* Wih_b = (const float*)d_in[6];
  const float* Whh_b = (const float*)d_in[7];
  const float* bih_b = (const float*)d_in[8];
  const float* bhh_b = (const float*)d_in[9];
  const float* c2_w1 = (const float*)d_in[10];
  const float* c2_g1 = (const float*)d_in[11];
  const float* c2_b1 = (const float*)d_in[12];
  const float* c2_w2 = (const float*)d_in[13];
  const float* c2_g2 = (const float*)d_in[14];
  const float* c2_b2 = (const float*)d_in[15];
  const float* cv_w1 = (const float*)d_in[16];
  const float* cv_g1 = (const float*)d_in[17];
  const float* cv_b1 = (const float*)d_in[18];
  const float* cv_w2 = (const float*)d_in[19];
  const float* cv_g2 = (const float*)d_in[20];
  const float* cv_b2 = (const float*)d_in[21];

  // ---- workspace layout (~107 MB, aliased; round-6 layout) ----
  char* base = (char*)d_ws;
  const size_t SLOTB = 16777216ull;                 // bf16 activation slot
  __hip_bfloat16* Xb  = (__hip_bfloat16*)(base);
  __hip_bfloat16* Sb  = (__hip_bfloat16*)(base);
  __hip_bfloat16* XG  = (__hip_bfloat16*)(base + SLOTB);
  __hip_bfloat16* D2  = (__hip_bfloat16*)(base + SLOTB);
  __hip_bfloat16* D2b = (__hip_bfloat16*)(base + 2*SLOTB);
  __hip_bfloat16* RT  = (__hip_bfloat16*)(base + SLOTB + 67108864ull);
  __hip_bfloat16* D1  = RT;
  char* wq = base + SLOTB + 67108864ull + SLOTB;
  __hip_bfloat16* wihc  = (__hip_bfloat16*)wq;
  float*          biasc = (float*)(wq + 524288);
  char* cw = wq + 528384;
  __hip_bfloat16* w1f    = (__hip_bfloat16*)(cw);
  __hip_bfloat16* w1full = (__hip_bfloat16*)(cw + 1179648);
  __hip_bfloat16* w2r    = (__hip_bfloat16*)(cw + 3538944);
  __hip_bfloat16* wv1    = (__hip_bfloat16*)(cw + 4718592);
  __hip_bfloat16* wv2    = (__hip_bfloat16*)(cw + 5308416);

  // weight prep
  k_wih_prep<<<1024, 256, 0, stream>>>(Wih_f, Wih_b, bih_f, bhh_f, bih_b, bhh_b,
                                       wihc, biasc);
  k_wrefmt_bf16<<<(9*256*256+255)/256, 256, 0, stream>>>(c2_w1, w1f,    256, 256, 1);
  k_wrefmt_bf16<<<(9*512*256+255)/256, 256, 0, stream>>>(c2_w1, w1full, 512, 256, 0);
  k_wrefmt_bf16<<<(9*256*256+255)/256, 256, 0, stream>>>(c2_w2, w2r,    256, 256, 0);
  k_wrefmt_bf16<<<(9*256*128+255)/256, 256, 0, stream>>>(cv_w1, wv1,    256, 128, 0);
  k_wrefmt_bf16<<<(9*128*128+255)/256, 256, 0, stream>>>(cv_w2, wv2,    128, 128, 0);

  // upsample + concat -> Xb (NHWC bf16)
  k_upcat<<<32768, 256, 0, stream>>>(x1, x2, Xb);

  // pass 1 (rows): xg = Xb @ Wih^T + b ; recurrent -> RT (transposed layout)
  k_xg_gemm<<<dim3(256, 8), 256, 0, stream>>>(Xb, wihc, biasc, XG);
  k_lstm_rec<<<dim3(128, 2), 256, 0, stream>>>(XG, Whh_f, Whh_b, RT);
  // pass 2 (cols): xg = RT @ Wih^T + b ; recurrent -> Sb (NHWC layout)
  k_xg_gemm<<<dim3(256, 8), 256, 0, stream>>>(RT, wihc, biasc, XG);
  k_lstm_rec<<<dim3(128, 2), 256, 0, stream>>>(XG, Whh_f, Whh_b, Sb);

  // x_site = double_conv(concat([S,S])) with folded first conv
  k_conv3_v3<<<dim3(128,4), 256, 0, stream>>>(Sb, nullptr, w1f, c2_g1, c2_b1,
                                              nullptr, D1, 256, 256, 0);      // T1
  k_conv3_v3<<<dim3(128,4), 256, 0, stream>>>(D1, nullptr, w2r, c2_g2, c2_b2,
                                              nullptr, D2, 256, 256, 0);      // XS
  // x = double_conv(concat([S, XS]))
  k_conv3_v3<<<dim3(128,4), 256, 0, stream>>>(Sb, D2, w1full, c2_g1, c2_b1,
                                              nullptr, D2b, 512, 256, 0);     // T2
  k_conv3_v3<<<dim3(128,4), 256, 0, stream>>>(D2b, nullptr, w2r, c2_g2, c2_b2,
                                              nullptr, D1, 256, 256, 0);      // Y
  // final double_conv (cv); last conv writes fp32 NCHW to d_out
  k_conv3_v3<<<dim3(128,2), 256, 0, stream>>>(D1, nullptr, wv1, cv_g1, cv_b1,
                                              nullptr, D2, 256, 128, 0);      // Z
  k_conv3_v3<<<dim3(128,2), 256, 0, stream>>>(D2, nullptr, wv2, cv_g2, cv_b2,
                                              (float*)d_out, nullptr, 128, 128, 1);
}